// Round 2
// baseline (88.222 us; speedup 1.0000x reference)
//
#include <hip/hip_runtime.h>

#define NCLS 7

// ws layout (4-byte slots):
//   [0] int   anchor        [1] int   a_cls
//   [2] float pos_num       [3] float neg_num
//   [4] float inv_norm(anc_t) [5] inv_norm(anc_v) [6] inv_norm(anc_a)
//   [7] pad
//   [8] int   tail counter (zeroed by prep each call)
//   [9..15] pad
//   [16..]   per-block partials: (pos, neg) pairs
struct Hdr {
    int   anchor;
    int   a_cls;
    float pos_num;
    float neg_num;
    float inv_at;
    float inv_av;
    float inv_aa;
    int   pad;
};

__device__ __forceinline__ float dot4(float4 a, float4 b) {
    return a.x * b.x + a.y * b.y + a.z * b.z + a.w * b.w;
}

// ---------------------------------------------------------------------------
// Kernel A: one block, one pass over labels. Per-thread REGISTER histogram +
// per-class min index (no atomics at all), int4 loads, shuffle reduce.
// Then waves 0..2 compute the 3 anchor-row inverse norms.
// ---------------------------------------------------------------------------
__global__ __launch_bounds__(256) void prep_kernel(
    const int* __restrict__ label,
    const float* __restrict__ s_t,
    const float* __restrict__ s_v,
    const float* __restrict__ s_a,
    int B, int D, float* __restrict__ ws)
{
    const int tid  = threadIdx.x;
    const int w    = tid >> 6;
    const int lane = tid & 63;

    int cnt[NCLS];
    int mn[NCLS];
#pragma unroll
    for (int k = 0; k < NCLS; ++k) { cnt[k] = 0; mn[k] = 0x7fffffff; }

    const int4* lab4 = (const int4*)label;
    const int n4 = B >> 2;
    for (int j = tid; j < n4; j += 256) {
        int4 L = lab4[j];
        const int base = j << 2;
        int ls[4] = { L.x, L.y, L.z, L.w };
#pragma unroll
        for (int e = 0; e < 4; ++e) {
#pragma unroll
            for (int k = 0; k < NCLS; ++k) {
                if (ls[e] == k) { cnt[k]++; mn[k] = min(mn[k], base + e); }
            }
        }
    }
    // tail (B not multiple of 4)
    for (int i = (n4 << 2) + tid; i < B; i += 256) {
        int l = label[i];
#pragma unroll
        for (int k = 0; k < NCLS; ++k)
            if (l == k) { cnt[k]++; mn[k] = min(mn[k], i); }
    }

#pragma unroll
    for (int k = 0; k < NCLS; ++k) {
        for (int off = 32; off; off >>= 1) {
            cnt[k] += __shfl_xor(cnt[k], off);
            mn[k]   = min(mn[k], __shfl_xor(mn[k], off));
        }
    }

    __shared__ int s_cnt[4][NCLS], s_mn[4][NCLS];
    __shared__ int s_anchor;
    if (lane == 0) {
#pragma unroll
        for (int k = 0; k < NCLS; ++k) { s_cnt[w][k] = cnt[k]; s_mn[w][k] = mn[k]; }
    }
    __syncthreads();

    if (tid == 0) {
        int hist[NCLS], mini[NCLS];
#pragma unroll
        for (int k = 0; k < NCLS; ++k) {
            hist[k] = s_cnt[0][k] + s_cnt[1][k] + s_cnt[2][k] + s_cnt[3][k];
            mini[k] = min(min(s_mn[0][k], s_mn[1][k]), min(s_mn[2][k], s_mn[3][k]));
        }
        // jnp.argmax(counts > 1): first class with count>1, else 0
        int c = 0;
#pragma unroll
        for (int k = NCLS - 1; k >= 0; --k) if (hist[k] > 1) c = k;
        s_anchor = mini[c];

        Hdr* h = (Hdr*)ws;
        h->anchor  = mini[c];
        h->a_cls   = c;
        float pn   = (float)hist[c];
        h->pos_num = pn;
        h->neg_num = (float)B - pn;
        ((int*)ws)[8] = 0;   // tail counter for the fused reduction
    }
    __syncthreads();

    // waves 0..2: inverse norm of one anchor row each
    const int anchor = s_anchor;
    if (w < 3) {
        const float* src = (w == 0) ? s_t : (w == 1) ? s_v : s_a;
        const float4* row = (const float4*)(src + (size_t)anchor * D);
        const int nvec = D >> 2;
        float s = 0.f;
        for (int j = lane; j < nvec; j += 64) {
            float4 x = row[j];
            s += dot4(x, x);
        }
        for (int off = 32; off; off >>= 1) s += __shfl_xor(s, off);
        if (lane == 0) ((float*)ws)[4 + w] = rsqrtf(s);
    }
}

// ---------------------------------------------------------------------------
// Kernel B: one wave per row, streams 3 modality rows (float4), 9 accumulators
// (2 cross-anchor dots + 1 sumsq per modality), shuffle reduce, per-block
// (pos,neg) partial. Tail reduction fused via last-block-done counter —
// deterministic: whichever block is last reads the identical, fully-written
// partials array in a fixed order.
// ---------------------------------------------------------------------------
__global__ __launch_bounds__(256) void main_kernel(
    const int* __restrict__ label,
    const float* __restrict__ s_t,
    const float* __restrict__ s_v,
    const float* __restrict__ s_a,
    int B, int D, float* __restrict__ ws, float* __restrict__ out)
{
    const Hdr* h = (const Hdr*)ws;
    volatile float* partials = (volatile float*)(ws + 16);
    int* counter = (int*)ws + 8;

    const int   anchor = h->anchor;
    const int   acls   = h->a_cls;
    const float inv_at = h->inv_at;
    const float inv_av = h->inv_av;
    const float inv_aa = h->inv_aa;

    const int w = threadIdx.x >> 6, lane = threadIdx.x & 63;
    const int r = blockIdx.x * 4 + w;

    __shared__ float pos_part[4], neg_part[4];
    __shared__ int   s_isLast;

    float rowtot = 0.f;
    bool  isPos = false, isNeg = false;

    if (r < B) {
        const float4* rt = (const float4*)(s_t + (size_t)r * D);
        const float4* rv = (const float4*)(s_v + (size_t)r * D);
        const float4* ra = (const float4*)(s_a + (size_t)r * D);
        const float4* at = (const float4*)(s_t + (size_t)anchor * D);
        const float4* av = (const float4*)(s_v + (size_t)anchor * D);
        const float4* aa = (const float4*)(s_a + (size_t)anchor * D);

        float dt_a = 0.f, dt_v = 0.f, sq_t = 0.f;
        float dv_t = 0.f, dv_a = 0.f, sq_v = 0.f;
        float da_t = 0.f, da_v = 0.f, sq_a = 0.f;

        const int nvec = D >> 2;
#pragma unroll 4
        for (int j = lane; j < nvec; j += 64) {
            float4 t  = rt[j], v  = rv[j], a  = ra[j];
            float4 bt = at[j], bv = av[j], ba = aa[j];
            dt_a += dot4(t, ba);
            dt_v += dot4(t, bv);
            sq_t += dot4(t, t);
            dv_t += dot4(v, bt);
            dv_a += dot4(v, ba);
            sq_v += dot4(v, v);
            da_t += dot4(a, bt);
            da_v += dot4(a, bv);
            sq_a += dot4(a, a);
        }
        for (int off = 32; off; off >>= 1) {
            dt_a += __shfl_xor(dt_a, off);
            dt_v += __shfl_xor(dt_v, off);
            sq_t += __shfl_xor(sq_t, off);
            dv_t += __shfl_xor(dv_t, off);
            dv_a += __shfl_xor(dv_a, off);
            sq_v += __shfl_xor(sq_v, off);
            da_t += __shfl_xor(da_t, off);
            da_v += __shfl_xor(da_v, off);
            sq_a += __shfl_xor(sq_a, off);
        }
        if (lane == 0) {
            float inv_t = rsqrtf(sq_t);
            float inv_v = rsqrtf(sq_v);
            float inv_a = rsqrtf(sq_a);
            rowtot = inv_t * (dt_a * inv_aa + dt_v * inv_av)
                   + inv_v * (dv_t * inv_at + dv_a * inv_aa)
                   + inv_a * (da_t * inv_at + da_v * inv_av);
            int lab = label[r];
            isPos = (lab == acls) && (r != anchor);
            isNeg = (lab != acls);
        }
    }

    if (lane == 0) {
        pos_part[w] = isPos ? rowtot : 0.f;
        neg_part[w] = isNeg ? rowtot : 0.f;
    }
    __syncthreads();

    if (threadIdx.x == 0) {
        float p = pos_part[0] + pos_part[1] + pos_part[2] + pos_part[3];
        float n = neg_part[0] + neg_part[1] + neg_part[2] + neg_part[3];
        partials[2 * blockIdx.x]     = p;
        partials[2 * blockIdx.x + 1] = n;
        __threadfence();                       // release partials (device scope)
        int old = atomicAdd(counter, 1);
        s_isLast = (old == (int)gridDim.x - 1);
    }
    __syncthreads();

    if (s_isLast) {
        __threadfence();                       // acquire other blocks' partials
        float p = 0.f, n = 0.f;
        const int nb = gridDim.x;
        for (int i = threadIdx.x; i < nb; i += 256) {
            p += partials[2 * i];
            n += partials[2 * i + 1];
        }
        for (int off = 32; off; off >>= 1) {
            p += __shfl_xor(p, off);
            n += __shfl_xor(n, off);
        }
        __shared__ float pp[4], nn[4];
        if (lane == 0) { pp[w] = p; nn[w] = n; }
        __syncthreads();
        if (threadIdx.x == 0) {
            float P = pp[0] + pp[1] + pp[2] + pp[3];
            float N = nn[0] + nn[1] + nn[2] + nn[3];
            out[0] = (6.0f - P / h->pos_num + N / h->neg_num) / 3.0f;
        }
    }
}

extern "C" void kernel_launch(void* const* d_in, const int* in_sizes, int n_in,
                              void* d_out, int out_size, void* d_ws, size_t ws_size,
                              hipStream_t stream) {
    const int*   label = (const int*)d_in[0];
    const float* s_t   = (const float*)d_in[1];
    const float* s_v   = (const float*)d_in[2];
    const float* s_a   = (const float*)d_in[3];

    const int B = in_sizes[0];
    const int D = in_sizes[1] / B;   // 1024

    float* ws  = (float*)d_ws;
    float* out = (float*)d_out;

    const int nblocks = (B + 3) / 4; // one wave per row, 4 waves per block

    prep_kernel<<<1, 256, 0, stream>>>(label, s_t, s_v, s_a, B, D, ws);
    main_kernel<<<nblocks, 256, 0, stream>>>(label, s_t, s_v, s_a, B, D, ws, out);
}

// Round 3
// 40.775 us; speedup vs baseline: 2.1636x; 2.1636x over previous
//
#include <hip/hip_runtime.h>

#define NCLS 7

// ws layout (4-byte slots):
//   [0] int   anchor        [1] int   a_cls
//   [2] float pos_num       [3] float neg_num
//   [4] float inv_norm(anc_t) [5] inv_norm(anc_v) [6] inv_norm(anc_a)
//   [7..15] pad
//   [16..]   per-block partials: float2 (pos, neg) per row-block
struct Hdr {
    int   anchor;
    int   a_cls;
    float pos_num;
    float neg_num;
    float inv_at;
    float inv_av;
    float inv_aa;
    int   pad;
};

__device__ __forceinline__ float dot4(float4 a, float4 b) {
    return a.x * b.x + a.y * b.y + a.z * b.z + a.w * b.w;
}

// ---------------------------------------------------------------------------
// Kernel A: one block, one pass over labels. Per-thread register histogram +
// per-class min index (no atomics), int4 loads, shuffle reduce.
// Then waves 0..2 compute the 3 anchor-row inverse norms.
// ---------------------------------------------------------------------------
__global__ __launch_bounds__(256) void prep_kernel(
    const int* __restrict__ label,
    const float* __restrict__ s_t,
    const float* __restrict__ s_v,
    const float* __restrict__ s_a,
    int B, int D, float* __restrict__ ws)
{
    const int tid  = threadIdx.x;
    const int w    = tid >> 6;
    const int lane = tid & 63;

    int cnt[NCLS];
    int mn[NCLS];
#pragma unroll
    for (int k = 0; k < NCLS; ++k) { cnt[k] = 0; mn[k] = 0x7fffffff; }

    const int4* lab4 = (const int4*)label;
    const int n4 = B >> 2;
    for (int j = tid; j < n4; j += 256) {
        int4 L = lab4[j];
        const int base = j << 2;
        int ls[4] = { L.x, L.y, L.z, L.w };
#pragma unroll
        for (int e = 0; e < 4; ++e) {
#pragma unroll
            for (int k = 0; k < NCLS; ++k) {
                if (ls[e] == k) { cnt[k]++; mn[k] = min(mn[k], base + e); }
            }
        }
    }
    for (int i = (n4 << 2) + tid; i < B; i += 256) {
        int l = label[i];
#pragma unroll
        for (int k = 0; k < NCLS; ++k)
            if (l == k) { cnt[k]++; mn[k] = min(mn[k], i); }
    }

#pragma unroll
    for (int k = 0; k < NCLS; ++k) {
        for (int off = 32; off; off >>= 1) {
            cnt[k] += __shfl_xor(cnt[k], off);
            mn[k]   = min(mn[k], __shfl_xor(mn[k], off));
        }
    }

    __shared__ int s_cnt[4][NCLS], s_mn[4][NCLS];
    __shared__ int s_anchor;
    if (lane == 0) {
#pragma unroll
        for (int k = 0; k < NCLS; ++k) { s_cnt[w][k] = cnt[k]; s_mn[w][k] = mn[k]; }
    }
    __syncthreads();

    if (tid == 0) {
        int hist[NCLS], mini[NCLS];
#pragma unroll
        for (int k = 0; k < NCLS; ++k) {
            hist[k] = s_cnt[0][k] + s_cnt[1][k] + s_cnt[2][k] + s_cnt[3][k];
            mini[k] = min(min(s_mn[0][k], s_mn[1][k]), min(s_mn[2][k], s_mn[3][k]));
        }
        int c = 0;
#pragma unroll
        for (int k = NCLS - 1; k >= 0; --k) if (hist[k] > 1) c = k;
        s_anchor = mini[c];

        Hdr* h = (Hdr*)ws;
        h->anchor  = mini[c];
        h->a_cls   = c;
        float pn   = (float)hist[c];
        h->pos_num = pn;
        h->neg_num = (float)B - pn;
    }
    __syncthreads();

    const int anchor = s_anchor;
    if (w < 3) {
        const float* src = (w == 0) ? s_t : (w == 1) ? s_v : s_a;
        const float4* row = (const float4*)(src + (size_t)anchor * D);
        const int nvec = D >> 2;
        float s = 0.f;
        for (int j = lane; j < nvec; j += 64) {
            float4 x = row[j];
            s += dot4(x, x);
        }
        for (int off = 32; off; off >>= 1) s += __shfl_xor(s, off);
        if (lane == 0) ((float*)ws)[4 + w] = rsqrtf(s);
    }
}

// ---------------------------------------------------------------------------
// Kernel B: ONE BLOCK PER ROW. With D=1024 each thread owns exactly one
// float4 per stream: 6 independent loads (3 streaming + 3 L1-hot anchor),
// 9 dot4s, one 64-lane shuffle reduce, 4x9 floats through LDS, thread 0
// writes the row's (pos,neg) partial. 8192 blocks -> 4 resident batches/CU
// -> wave turnover hides load latency (round-2 kernel had none).
// ---------------------------------------------------------------------------
__global__ __launch_bounds__(256) void main_kernel(
    const int* __restrict__ label,
    const float* __restrict__ s_t,
    const float* __restrict__ s_v,
    const float* __restrict__ s_a,
    int B, int D, float* __restrict__ ws)
{
    const Hdr* h = (const Hdr*)ws;
    float2* partials = (float2*)(ws + 16);

    const int r    = blockIdx.x;
    const int tid  = threadIdx.x;
    const int w    = tid >> 6;
    const int lane = tid & 63;

    const int anchor = h->anchor;

    const float4* rt = (const float4*)(s_t + (size_t)r * D);
    const float4* rv = (const float4*)(s_v + (size_t)r * D);
    const float4* ra = (const float4*)(s_a + (size_t)r * D);
    const float4* at = (const float4*)(s_t + (size_t)anchor * D);
    const float4* av = (const float4*)(s_v + (size_t)anchor * D);
    const float4* aa = (const float4*)(s_a + (size_t)anchor * D);

    float dt_a = 0.f, dt_v = 0.f, sq_t = 0.f;
    float dv_t = 0.f, dv_a = 0.f, sq_v = 0.f;
    float da_t = 0.f, da_v = 0.f, sq_a = 0.f;

    const int nvec = D >> 2;          // 256 for D=1024 -> exactly one iter
    for (int j = tid; j < nvec; j += 256) {
        float4 t  = rt[j], v  = rv[j], a  = ra[j];
        float4 bt = at[j], bv = av[j], ba = aa[j];
        dt_a += dot4(t, ba);
        dt_v += dot4(t, bv);
        sq_t += dot4(t, t);
        dv_t += dot4(v, bt);
        dv_a += dot4(v, ba);
        sq_v += dot4(v, v);
        da_t += dot4(a, bt);
        da_v += dot4(a, bv);
        sq_a += dot4(a, a);
    }

    for (int off = 32; off; off >>= 1) {
        dt_a += __shfl_xor(dt_a, off);
        dt_v += __shfl_xor(dt_v, off);
        sq_t += __shfl_xor(sq_t, off);
        dv_t += __shfl_xor(dv_t, off);
        dv_a += __shfl_xor(dv_a, off);
        sq_v += __shfl_xor(sq_v, off);
        da_t += __shfl_xor(da_t, off);
        da_v += __shfl_xor(da_v, off);
        sq_a += __shfl_xor(sq_a, off);
    }

    __shared__ float red[4][9];
    if (lane == 0) {
        red[w][0] = dt_a; red[w][1] = dt_v; red[w][2] = sq_t;
        red[w][3] = dv_t; red[w][4] = dv_a; red[w][5] = sq_v;
        red[w][6] = da_t; red[w][7] = da_v; red[w][8] = sq_a;
    }
    __syncthreads();

    if (tid == 0) {
        float s[9];
#pragma unroll
        for (int k = 0; k < 9; ++k)
            s[k] = red[0][k] + red[1][k] + red[2][k] + red[3][k];

        float inv_t = rsqrtf(s[2]);
        float inv_v = rsqrtf(s[5]);
        float inv_a = rsqrtf(s[8]);
        float rowtot = inv_t * (s[0] * h->inv_aa + s[1] * h->inv_av)
                     + inv_v * (s[3] * h->inv_at + s[4] * h->inv_aa)
                     + inv_a * (s[6] * h->inv_at + s[7] * h->inv_av);

        int  lab   = label[r];
        bool isPos = (lab == h->a_cls) && (r != anchor);
        bool isNeg = (lab != h->a_cls);
        partials[r] = make_float2(isPos ? rowtot : 0.f, isNeg ? rowtot : 0.f);
    }
}

// ---------------------------------------------------------------------------
// Kernel C: deterministic reduction of B partial pairs -> scalar loss.
// loss = (6 - pos_total/pos_num + neg_total/neg_num) / 3
// ---------------------------------------------------------------------------
__global__ __launch_bounds__(1024) void finish_kernel(
    const float* __restrict__ ws, int B, float* __restrict__ out)
{
    const Hdr* h = (const Hdr*)ws;
    const float2* partials = (const float2*)(ws + 16);

    float p = 0.f, n = 0.f;
    for (int i = threadIdx.x; i < B; i += 1024) {
        float2 pr = partials[i];
        p += pr.x;
        n += pr.y;
    }
    for (int off = 32; off; off >>= 1) {
        p += __shfl_xor(p, off);
        n += __shfl_xor(n, off);
    }
    __shared__ float pp[16], nn[16];
    const int w = threadIdx.x >> 6, lane = threadIdx.x & 63;
    if (lane == 0) { pp[w] = p; nn[w] = n; }
    __syncthreads();
    if (threadIdx.x == 0) {
        float P = 0.f, N = 0.f;
#pragma unroll
        for (int k = 0; k < 16; ++k) { P += pp[k]; N += nn[k]; }
        out[0] = (6.0f - P / h->pos_num + N / h->neg_num) / 3.0f;
    }
}

extern "C" void kernel_launch(void* const* d_in, const int* in_sizes, int n_in,
                              void* d_out, int out_size, void* d_ws, size_t ws_size,
                              hipStream_t stream) {
    const int*   label = (const int*)d_in[0];
    const float* s_t   = (const float*)d_in[1];
    const float* s_v   = (const float*)d_in[2];
    const float* s_a   = (const float*)d_in[3];

    const int B = in_sizes[0];
    const int D = in_sizes[1] / B;   // 1024

    float* ws  = (float*)d_ws;
    float* out = (float*)d_out;

    prep_kernel<<<1, 256, 0, stream>>>(label, s_t, s_v, s_a, B, D, ws);
    main_kernel<<<B, 256, 0, stream>>>(label, s_t, s_v, s_a, B, D, ws);
    finish_kernel<<<1, 1024, 0, stream>>>(ws, B, out);
}

// Round 4
// 34.192 us; speedup vs baseline: 2.5802x; 1.1925x over previous
//
#include <hip/hip_runtime.h>

#define NCLS 7

// ws layout (4-byte slots):
//   [0] int   anchor        [1] int   a_cls
//   [2] float pos_num       [3] float neg_num
//   [4] float inv_norm(anc_t) [5] inv_norm(anc_v) [6] inv_norm(anc_a)
//   [7..15] pad
//   [16..]   per-row partials: float2 (pos, neg)
struct Hdr {
    int   anchor;
    int   a_cls;
    float pos_num;
    float neg_num;
    float inv_at;
    float inv_av;
    float inv_aa;
    int   pad;
};

__device__ __forceinline__ float dot4(float4 a, float4 b) {
    return a.x * b.x + a.y * b.y + a.z * b.z + a.w * b.w;
}

// ---------------------------------------------------------------------------
// Kernel A (1024 thr): one pass over labels with per-thread register
// histogram + per-class min index (no atomics), int4 loads; then 12 waves
// compute the 3 anchor-row inverse norms (4 waves per row, 1 float4/lane).
// ---------------------------------------------------------------------------
__global__ __launch_bounds__(1024) void prep_kernel(
    const int* __restrict__ label,
    const float* __restrict__ s_t,
    const float* __restrict__ s_v,
    const float* __restrict__ s_a,
    int B, int D, float* __restrict__ ws)
{
    const int tid  = threadIdx.x;
    const int w    = tid >> 6;
    const int lane = tid & 63;

    int cnt[NCLS];
    int mn[NCLS];
#pragma unroll
    for (int k = 0; k < NCLS; ++k) { cnt[k] = 0; mn[k] = 0x7fffffff; }

    const int4* lab4 = (const int4*)label;
    const int n4 = B >> 2;
    for (int j = tid; j < n4; j += 1024) {
        int4 L = lab4[j];
        const int base = j << 2;
        int ls[4] = { L.x, L.y, L.z, L.w };
#pragma unroll
        for (int e = 0; e < 4; ++e) {
#pragma unroll
            for (int k = 0; k < NCLS; ++k) {
                if (ls[e] == k) { cnt[k]++; mn[k] = min(mn[k], base + e); }
            }
        }
    }
    for (int i = (n4 << 2) + tid; i < B; i += 1024) {
        int l = label[i];
#pragma unroll
        for (int k = 0; k < NCLS; ++k)
            if (l == k) { cnt[k]++; mn[k] = min(mn[k], i); }
    }

#pragma unroll
    for (int k = 0; k < NCLS; ++k) {
        for (int off = 32; off; off >>= 1) {
            cnt[k] += __shfl_xor(cnt[k], off);
            mn[k]   = min(mn[k], __shfl_xor(mn[k], off));
        }
    }

    __shared__ int   s_cnt[16][NCLS], s_mn[16][NCLS];
    __shared__ int   s_anchor;
    __shared__ float s_norm[12];
    if (lane == 0) {
#pragma unroll
        for (int k = 0; k < NCLS; ++k) { s_cnt[w][k] = cnt[k]; s_mn[w][k] = mn[k]; }
    }
    __syncthreads();

    if (tid == 0) {
        int hist[NCLS], mini[NCLS];
#pragma unroll
        for (int k = 0; k < NCLS; ++k) {
            int hc = 0, mc = 0x7fffffff;
            for (int q = 0; q < 16; ++q) { hc += s_cnt[q][k]; mc = min(mc, s_mn[q][k]); }
            hist[k] = hc; mini[k] = mc;
        }
        // jnp.argmax(counts > 1): first class with count>1, else 0
        int c = 0;
#pragma unroll
        for (int k = NCLS - 1; k >= 0; --k) if (hist[k] > 1) c = k;
        s_anchor = mini[c];

        Hdr* h = (Hdr*)ws;
        h->anchor  = mini[c];
        h->a_cls   = c;
        float pn   = (float)hist[c];
        h->pos_num = pn;
        h->neg_num = (float)B - pn;
    }
    __syncthreads();

    // inverse norms of the 3 anchor rows: wave w<12 -> row w>>2, quarter w&3
    const int anchor = s_anchor;
    if (w < 12) {
        const int rw = w >> 2, qw = w & 3;
        const float* src = (rw == 0) ? s_t : (rw == 1) ? s_v : s_a;
        const float4* row = (const float4*)(src + (size_t)anchor * D);
        const int nvec = D >> 2;
        float s = 0.f;
        for (int j = qw * 64 + lane; j < nvec; j += 256) {
            float4 x = row[j];
            s += dot4(x, x);
        }
        for (int off = 32; off; off >>= 1) s += __shfl_xor(s, off);
        if (lane == 0) s_norm[w] = s;
    }
    __syncthreads();
    if (tid < 3)
        ((float*)ws)[4 + tid] = rsqrtf(s_norm[4 * tid] + s_norm[4 * tid + 1] +
                                       s_norm[4 * tid + 2] + s_norm[4 * tid + 3]);
}

// ---------------------------------------------------------------------------
// Kernel B: one block per row. Each thread: 6 float4 loads (3 streaming +
// 3 L1-hot anchor), 9 dot4s. Reduction restructured to FOUR block-reduces
// instead of nine: reduce the 3 sum-of-squares, broadcast inv norms via LDS,
// then each thread linearly folds its 6 partial dots (anchor norms are linear
// in rowtot) into ONE scalar and a single final reduce finishes the row.
// 54 -> 24 shuffle ops per thread (DS-pipe was the co-bottleneck).
// ---------------------------------------------------------------------------
__global__ __launch_bounds__(256) void main_kernel(
    const int* __restrict__ label,
    const float* __restrict__ s_t,
    const float* __restrict__ s_v,
    const float* __restrict__ s_a,
    int B, int D, float* __restrict__ ws)
{
    const Hdr* h = (const Hdr*)ws;
    float2* partials = (float2*)(ws + 16);

    const int r    = blockIdx.x;
    const int tid  = threadIdx.x;
    const int w    = tid >> 6;
    const int lane = tid & 63;

    const int lab    = label[r];      // uniform -> s_load, issued early
    const int anchor = h->anchor;

    const float4* rt = (const float4*)(s_t + (size_t)r * D);
    const float4* rv = (const float4*)(s_v + (size_t)r * D);
    const float4* ra = (const float4*)(s_a + (size_t)r * D);
    const float4* at = (const float4*)(s_t + (size_t)anchor * D);
    const float4* av = (const float4*)(s_v + (size_t)anchor * D);
    const float4* aa = (const float4*)(s_a + (size_t)anchor * D);

    float dt_a = 0.f, dt_v = 0.f, sq_t = 0.f;
    float dv_t = 0.f, dv_a = 0.f, sq_v = 0.f;
    float da_t = 0.f, da_v = 0.f, sq_a = 0.f;

    const int nvec = D >> 2;          // 256 for D=1024 -> exactly one iter
    for (int j = tid; j < nvec; j += 256) {
        float4 t  = rt[j], v  = rv[j], a  = ra[j];
        float4 bt = at[j], bv = av[j], ba = aa[j];
        dt_a += dot4(t, ba);
        dt_v += dot4(t, bv);
        sq_t += dot4(t, t);
        dv_t += dot4(v, bt);
        dv_a += dot4(v, ba);
        sq_v += dot4(v, v);
        da_t += dot4(a, bt);
        da_v += dot4(a, bv);
        sq_a += dot4(a, a);
    }

    // --- stage 1: block-reduce the three sum-of-squares, broadcast ---
    for (int off = 32; off; off >>= 1) {
        sq_t += __shfl_xor(sq_t, off);
        sq_v += __shfl_xor(sq_v, off);
        sq_a += __shfl_xor(sq_a, off);
    }
    __shared__ float red_sq[4][3];
    __shared__ float red_c[4];
    if (lane == 0) {
        red_sq[w][0] = sq_t; red_sq[w][1] = sq_v; red_sq[w][2] = sq_a;
    }
    __syncthreads();

    const float SQ_t = red_sq[0][0] + red_sq[1][0] + red_sq[2][0] + red_sq[3][0];
    const float SQ_v = red_sq[0][1] + red_sq[1][1] + red_sq[2][1] + red_sq[3][1];
    const float SQ_a = red_sq[0][2] + red_sq[1][2] + red_sq[2][2] + red_sq[3][2];
    const float inv_t = rsqrtf(SQ_t);
    const float inv_v = rsqrtf(SQ_v);
    const float inv_a = rsqrtf(SQ_a);

    // --- stage 2: fold 6 partial dots into one scalar per thread ---
    float combined = inv_t * (dt_a * h->inv_aa + dt_v * h->inv_av)
                   + inv_v * (dv_t * h->inv_at + dv_a * h->inv_aa)
                   + inv_a * (da_t * h->inv_at + da_v * h->inv_av);

    for (int off = 32; off; off >>= 1)
        combined += __shfl_xor(combined, off);
    if (lane == 0) red_c[w] = combined;
    __syncthreads();

    if (tid == 0) {
        float rowtot = red_c[0] + red_c[1] + red_c[2] + red_c[3];
        bool isPos = (lab == h->a_cls) && (r != anchor);
        bool isNeg = (lab != h->a_cls);
        partials[r] = make_float2(isPos ? rowtot : 0.f, isNeg ? rowtot : 0.f);
    }
}

// ---------------------------------------------------------------------------
// Kernel C: deterministic reduction of B partial pairs -> scalar loss.
// loss = (6 - pos_total/pos_num + neg_total/neg_num) / 3
// ---------------------------------------------------------------------------
__global__ __launch_bounds__(1024) void finish_kernel(
    const float* __restrict__ ws, int B, float* __restrict__ out)
{
    const Hdr* h = (const Hdr*)ws;
    const float2* partials = (const float2*)(ws + 16);

    float p = 0.f, n = 0.f;
    for (int i = threadIdx.x; i < B; i += 1024) {
        float2 pr = partials[i];
        p += pr.x;
        n += pr.y;
    }
    for (int off = 32; off; off >>= 1) {
        p += __shfl_xor(p, off);
        n += __shfl_xor(n, off);
    }
    __shared__ float pp[16], nn[16];
    const int w = threadIdx.x >> 6, lane = threadIdx.x & 63;
    if (lane == 0) { pp[w] = p; nn[w] = n; }
    __syncthreads();
    if (threadIdx.x == 0) {
        float P = 0.f, N = 0.f;
#pragma unroll
        for (int k = 0; k < 16; ++k) { P += pp[k]; N += nn[k]; }
        out[0] = (6.0f - P / h->pos_num + N / h->neg_num) / 3.0f;
    }
}

extern "C" void kernel_launch(void* const* d_in, const int* in_sizes, int n_in,
                              void* d_out, int out_size, void* d_ws, size_t ws_size,
                              hipStream_t stream) {
    const int*   label = (const int*)d_in[0];
    const float* s_t   = (const float*)d_in[1];
    const float* s_v   = (const float*)d_in[2];
    const float* s_a   = (const float*)d_in[3];

    const int B = in_sizes[0];
    const int D = in_sizes[1] / B;   // 1024

    float* ws  = (float*)d_ws;
    float* out = (float*)d_out;

    prep_kernel<<<1, 1024, 0, stream>>>(label, s_t, s_v, s_a, B, D, ws);
    main_kernel<<<B, 256, 0, stream>>>(label, s_t, s_v, s_a, B, D, ws);
    finish_kernel<<<1, 1024, 0, stream>>>(ws, B, out);
}